// Round 12
// baseline (568.526 us; speedup 1.0000x reference)
//
#include <hip/hip_runtime.h>

#define N_TOK 8192
#define KDIM  4096
#define NE    16
#define NH    2                    // K halves (split-K)
#define KH    (KDIM / NH)          // 2048
#define TPB   32                   // tokens per block (2 per wave, 16 waves)
#define GROW  2052                 // gateT row stride in floats (2048 + 4 pad)
#define GROW4 513                  // ... in float4
#define SCOFF (NE * GROW)          // scratch offset: 32832 floats

// R18: whole-half gate resident in LDS; zero barriers in the k-loop.
// R16/R17 post-mortem: allocator pins 64 VGPR in 256-thr/33KB kernels
// (targets 8 waves/EU; waves_per_eu attr ignored) -> acc[4][16] spills
// (WRITE 70-133MB). Same amortization WITHOUT big acc: 2 tokens/wave over
// HALF of K == 4 tokens over full K in gate-reads-per-token. Structure:
// 1024-thread block stages its K-half of gate (128KB, transposed) into LDS
// ONCE (one barrier), then 16 waves stream x fill-shaped (1KB/instr) with
// NO barriers / NO per-chunk staging / NO drains -- the shared property of
// every 70-107us variant so far. LDS 144KB -> 1 block/CU = 16 waves/CU
// (measured TLP optimum); occupancy LDS-capped at 4 waves/EU -> allocator
// budget becomes 128 VGPR naturally (demand ~76, acc[2][16]=32). Per-CU:
// x-HBM 21us, gate-LDS 2MB ~=8us, issue ~9us, all overlapped, no barriers.
// Prediction: logits 83 -> 30-40us, VGPR 80-100 (>64 = unlock validity),
// WRITE -> ~1-2MB, total -> 155-170. VGPR=64+spill => jail is structural;
// 55-70us clean => barrier theory wrong.
__global__ __launch_bounds__(1024)
void router_logits(const float* __restrict__ x, const float* __restrict__ gate,
                   float* __restrict__ ws) {
  __shared__ __align__(16) float glds[NE * GROW + 16 * 8 * 2 * NE];  // 144.25 KB
  const int tid  = threadIdx.x;
  const int lane = tid & 63;
  const int w    = __builtin_amdgcn_readfirstlane(tid >> 6);   // 0..15
  const int g    = blockIdx.x >> 1;                // token group (256)
  const int h    = blockIdx.x & 1;                 // K half
  const int t0   = g * TPB;
  const int tokb = t0 + w * 2;                     // wave's 2 tokens

  // ---- prologue: stage gate K-half (2048 k x 16 e = 128 KB), transposed ----
  // 32768 f4 by 1024 threads = 32 f4/thread, 4 passes of 8 to bound regs.
  {
    const float4* gsrc = (const float4*)gate + (size_t)h * (KH * NE / 4);
    for (int p = 0; p < 4; ++p) {
      float4 gr[8];
#pragma unroll
      for (int u = 0; u < 8; ++u) gr[u] = gsrc[p * 8192 + u * 1024 + tid];
#pragma unroll
      for (int u = 0; u < 8; ++u) {
        int i = p * 8192 + u * 1024 + tid;
        int k = i >> 2, j = i & 3;                 // gate row k, f4 j (4 e each)
        glds[(4 * j + 0) * GROW + k] = gr[u].x;
        glds[(4 * j + 1) * GROW + k] = gr[u].y;
        glds[(4 * j + 2) * GROW + k] = gr[u].z;
        glds[(4 * j + 3) * GROW + k] = gr[u].w;
      }
    }
  }

  const float4* xr0 = (const float4*)(x + (size_t)(tokb + 0) * KDIM) + h * (KH / 4);
  const float4* xr1 = (const float4*)(x + (size_t)(tokb + 1) * KDIM) + h * (KH / 4);
  float4 xc0 = xr0[lane], xc1 = xr1[lane];         // step 0 (issued pre-barrier)

  float acc[2][NE];
#pragma unroll
  for (int t = 0; t < 2; ++t)
#pragma unroll
    for (int e = 0; e < NE; ++e) acc[t][e] = 0.f;

  __syncthreads();                                 // gate resident; ONLY barrier

  // ---- k-loop: 8 steps x 256 k, barrier-free ----
  const float4* gl4 = (const float4*)glds;         // row e -> gl4[e*513 + k4]
#pragma unroll
  for (int c = 0; c < 8; ++c) {
    float4 xn0 = xc0, xn1 = xc1;                   // next-step prefetch (2-deep)
    if (c + 1 < 8) { xn0 = xr0[(c + 1) * 64 + lane]; xn1 = xr1[(c + 1) * 64 + lane]; }
#pragma unroll
    for (int eq = 0; eq < 4; ++eq) {
      const float4 ge0 = gl4[(eq * 4 + 0) * GROW4 + c * 64 + lane];
      const float4 ge1 = gl4[(eq * 4 + 1) * GROW4 + c * 64 + lane];
      const float4 ge2 = gl4[(eq * 4 + 2) * GROW4 + c * 64 + lane];
      const float4 ge3 = gl4[(eq * 4 + 3) * GROW4 + c * 64 + lane];
      acc[0][eq*4+0] += xc0.x*ge0.x + xc0.y*ge0.y + xc0.z*ge0.z + xc0.w*ge0.w;
      acc[0][eq*4+1] += xc0.x*ge1.x + xc0.y*ge1.y + xc0.z*ge1.z + xc0.w*ge1.w;
      acc[0][eq*4+2] += xc0.x*ge2.x + xc0.y*ge2.y + xc0.z*ge2.z + xc0.w*ge2.w;
      acc[0][eq*4+3] += xc0.x*ge3.x + xc0.y*ge3.y + xc0.z*ge3.z + xc0.w*ge3.w;
      acc[1][eq*4+0] += xc1.x*ge0.x + xc1.y*ge0.y + xc1.z*ge0.z + xc1.w*ge0.w;
      acc[1][eq*4+1] += xc1.x*ge1.x + xc1.y*ge1.y + xc1.z*ge1.z + xc1.w*ge1.w;
      acc[1][eq*4+2] += xc1.x*ge2.x + xc1.y*ge2.y + xc1.z*ge2.z + xc1.w*ge2.w;
      acc[1][eq*4+3] += xc1.x*ge3.x + xc1.y*ge3.y + xc1.z*ge3.z + xc1.w*ge3.w;
    }
    xc0 = xn0; xc1 = xn1;
  }

  // ---- epilogue: butterfly over lane bits 3..5, gather 8 k-groups ----
#pragma unroll
  for (int t = 0; t < 2; ++t)
#pragma unroll
    for (int e = 0; e < NE; ++e) {
      acc[t][e] += __shfl_xor(acc[t][e], 32, 64);
      acc[t][e] += __shfl_xor(acc[t][e], 16, 64);
      acc[t][e] += __shfl_xor(acc[t][e],  8, 64);
    }
  float* sc = glds + SCOFF;                        // separate 16 KB region
  if (lane < 8) {
#pragma unroll
    for (int t = 0; t < 2; ++t)
#pragma unroll
      for (int e = 0; e < NE; ++e)
        sc[((w * 8 + lane) * 2 + t) * 16 + e] = acc[t][e];
  }
  __syncthreads();
  if (tid < 512) {                                 // 32 tokens x 16 e
    int tok = tid >> 4, e = tid & 15;
    int ww = tok >> 1, tt = tok & 1;
    float s = 0.f;
#pragma unroll
    for (int grp = 0; grp < 8; ++grp)
      s += sc[((ww * 8 + grp) * 2 + tt) * 16 + e];
    ws[((size_t)h * N_TOK + t0 + tok) * NE + e] = s;   // contiguous 2 KB/block
  }
}

// Sum 2 half-partials, top-2 (earliest-index tie-break = jax top_k),
// sigmoid, scatter into (E,N) scores; token_indices[e][t] = t (as float).
__global__ __launch_bounds__(256)
void router_finalize(const float* __restrict__ ws, float* __restrict__ out) {
  int t = blockIdx.x * 256 + threadIdx.x;
  const float4* r0p = (const float4*)(ws + (size_t)t * NE);
  const float4* r1p = (const float4*)(ws + ((size_t)N_TOK + t) * NE);
  float l[NE];
#pragma unroll
  for (int j = 0; j < 4; ++j) {
    float4 a = r0p[j], b = r1p[j];
    l[j*4+0] = a.x + b.x; l[j*4+1] = a.y + b.y;
    l[j*4+2] = a.z + b.z; l[j*4+3] = a.w + b.w;
  }
  int i1 = 0; float v1 = l[0];
#pragma unroll
  for (int e = 1; e < NE; ++e) { if (l[e] > v1) { v1 = l[e]; i1 = e; } }
  int i2 = -1; float v2 = -1e30f;
#pragma unroll
  for (int e = 0; e < NE; ++e) { if (e != i1 && l[e] > v2) { v2 = l[e]; i2 = e; } }
  float s1 = 1.f / (1.f + __expf(-v1));
  float s2 = 1.f / (1.f + __expf(-v2));
  float* scores = out;
  float* tix    = out + (size_t)NE * N_TOK;
  float tf = (float)t;
#pragma unroll
  for (int e = 0; e < NE; ++e) {                   // coalesced across lanes per e
    scores[(size_t)e * N_TOK + t] = (e == i1) ? s1 : ((e == i2) ? s2 : 0.f);
    tix[(size_t)e * N_TOK + t]    = tf;
  }
}

extern "C" void kernel_launch(void* const* d_in, const int* in_sizes, int n_in,
                              void* d_out, int out_size, void* d_ws, size_t ws_size,
                              hipStream_t stream) {
  const float* x    = (const float*)d_in[0];
  const float* gate = (const float*)d_in[1];
  float* out = (float*)d_out;
  float* ws  = (float*)d_ws;   // needs NH*N_TOK*NE*4 = 1 MB
  router_logits<<<dim3(N_TOK / TPB * NH), dim3(1024), 0, stream>>>(x, gate, ws);
  router_finalize<<<dim3(N_TOK / 256), dim3(256), 0, stream>>>(ws, out);
}

// Round 13
// 199.866 us; speedup vs baseline: 2.8445x; 2.8445x over previous
//
#include <hip/hip_runtime.h>

#define N_TOK 8192
#define KDIM  4096
#define NE    16
#define TPB   8                    // tokens per block (2 per wave)
#define CHUNK 256                  // k per chunk
#define NC    (KDIM / CHUNK)       // 16 chunks
#define GSTR  256                  // gateT row stride in floats (NO pad: 32KB LDS)
#define GBUF  (NE * GSTR)          // 4096 floats per buffer

// R19: R15's structure, registered-dieted to fit the 64-VGPR jail.
// Law established over R16/R17/R18: compiler pins VGPR=64 (8 waves/EU) and
// SPILLS anything above; launch_bounds(,4) and waves_per_eu(4,4) are both
// ignored (R18: 871MB spill writes, 437us, absmax flip). Retro-insight:
// R15's demand was ~100 regs -> R15 was silently spilling ~30; its 60-70us
// was spill-throttled. R19 cuts demand to ~64: (1) drop xn[2] -- reload xc
// in place after last use (latency hides under staging wait + barrier);
// (2) load gr[4] LATE (right before the LDS write) -- ~500cy exposure
// covered by cross-block TLP; (3) GSTR 260->256: reads stay conflict-free
// (lane-stride-1), transpose-writes go 4-way (~1.58x on 16 b32 writes,
// negligible), LDS = exactly 32KB -> 5 blocks/CU = 20 waves/CU, 5
// independent barrier domains. Same arithmetic as R15 (absmax 0.0).
// Validity: WRITE_SIZE -> ~2MB (spill gone), FETCH ~140MB, LDS=32768.
// Prediction: logits -> 35-45us, VALUBusy 20-30%, total -> ~165-178.
// Clean-but-flat => spill theory dead, write the roofline argument.
__global__ __launch_bounds__(256)
void router_logits(const float* __restrict__ x, const float* __restrict__ gate,
                   float* __restrict__ ws) {
  __shared__ __align__(16) float glds[2 * GBUF];   // 32768 B exactly
  const int tid  = threadIdx.x;
  const int lane = tid & 63;
  const int w    = __builtin_amdgcn_readfirstlane(tid >> 6);
  const int t0   = blockIdx.x * TPB;
  const int tokb = t0 + w * 2;                     // wave's 2 tokens

  const float4* gsrc = (const float4*)gate;        // f4 idx: k*4 + j

  // ---- prologue: stage gate chunk 0 into buf0 (transposed) ----
  {
    float4 gr[4];
#pragma unroll
    for (int u = 0; u < 4; ++u) gr[u] = gsrc[u * 256 + tid];
#pragma unroll
    for (int u = 0; u < 4; ++u) {
      int f4 = u * 256 + tid, k = f4 >> 2, j = f4 & 3;
      glds[(4 * j + 0) * GSTR + k] = gr[u].x;
      glds[(4 * j + 1) * GSTR + k] = gr[u].y;
      glds[(4 * j + 2) * GSTR + k] = gr[u].z;
      glds[(4 * j + 3) * GSTR + k] = gr[u].w;
    }
  }

  const float4* xr0 = (const float4*)(x + (size_t)(tokb + 0) * KDIM);
  const float4* xr1 = (const float4*)(x + (size_t)(tokb + 1) * KDIM);
  float4 xc0 = xr0[lane], xc1 = xr1[lane];         // chunk 0: 1KB/instr/wave

  float acc[2][NE];
#pragma unroll
  for (int t = 0; t < 2; ++t)
#pragma unroll
    for (int e = 0; e < NE; ++e) acc[t][e] = 0.f;

  __syncthreads();                                 // buf0 visible

  const float4* gl4 = (const float4*)glds;
  for (int c = 0; c < NC; ++c) {
    const int b = c & 1;

    // compute chunk c from buf b: 16 ds_read_b128 + 256 FMA per lane
    const float4* gb4 = gl4 + b * (GBUF / 4);
#pragma unroll
    for (int eq = 0; eq < 4; ++eq) {
      const float4 ge0 = gb4[(eq * 4 + 0) * 64 + lane];
      const float4 ge1 = gb4[(eq * 4 + 1) * 64 + lane];
      const float4 ge2 = gb4[(eq * 4 + 2) * 64 + lane];
      const float4 ge3 = gb4[(eq * 4 + 3) * 64 + lane];
      acc[0][eq*4+0] += xc0.x*ge0.x + xc0.y*ge0.y + xc0.z*ge0.z + xc0.w*ge0.w;
      acc[0][eq*4+1] += xc0.x*ge1.x + xc0.y*ge1.y + xc0.z*ge1.z + xc0.w*ge1.w;
      acc[0][eq*4+2] += xc0.x*ge2.x + xc0.y*ge2.y + xc0.z*ge2.z + xc0.w*ge2.w;
      acc[0][eq*4+3] += xc0.x*ge3.x + xc0.y*ge3.y + xc0.z*ge3.z + xc0.w*ge3.w;
      acc[1][eq*4+0] += xc1.x*ge0.x + xc1.y*ge0.y + xc1.z*ge0.z + xc1.w*ge0.w;
      acc[1][eq*4+1] += xc1.x*ge1.x + xc1.y*ge1.y + xc1.z*ge1.z + xc1.w*ge1.w;
      acc[1][eq*4+2] += xc1.x*ge2.x + xc1.y*ge2.y + xc1.z*ge2.z + xc1.w*ge2.w;
      acc[1][eq*4+3] += xc1.x*ge3.x + xc1.y*ge3.y + xc1.z*ge3.z + xc1.w*ge3.w;
    }

    if (c + 1 < NC) {
      // reload xc in place (WAR: issues after last FMA reading old xc);
      // consumed next iteration -> latency hides under staging + barrier
      xc0 = xr0[(c + 1) * 64 + lane];
      xc1 = xr1[(c + 1) * 64 + lane];
      // stage gate chunk c+1 into buf b^1; gr loaded LATE (short live range)
      float4 gr[4];
#pragma unroll
      for (int u = 0; u < 4; ++u) gr[u] = gsrc[(c + 1) * 1024 + u * 256 + tid];
      float* dst = glds + (b ^ 1) * GBUF;
#pragma unroll
      for (int u = 0; u < 4; ++u) {
        int f4 = u * 256 + tid, k = f4 >> 2, j = f4 & 3;
        dst[(4 * j + 0) * GSTR + k] = gr[u].x;
        dst[(4 * j + 1) * GSTR + k] = gr[u].y;
        dst[(4 * j + 2) * GSTR + k] = gr[u].z;
        dst[(4 * j + 3) * GSTR + k] = gr[u].w;
      }
    }
    __syncthreads();   // buf b readers done + buf b^1 writes visible
  }

  // ---- epilogue: butterfly + 8-group gather (same arithmetic as R15) ----
#pragma unroll
  for (int t = 0; t < 2; ++t)
#pragma unroll
    for (int e = 0; e < NE; ++e) {
      acc[t][e] += __shfl_xor(acc[t][e], 32, 64);
      acc[t][e] += __shfl_xor(acc[t][e], 16, 64);
      acc[t][e] += __shfl_xor(acc[t][e],  8, 64);
    }
  if (lane < 8) {                                  // reuse glds[0..1023]
#pragma unroll
    for (int t = 0; t < 2; ++t)
#pragma unroll
      for (int e = 0; e < NE; ++e)
        glds[((w * 8 + lane) * 2 + t) * 16 + e] = acc[t][e];
  }
  __syncthreads();
  if (tid < 128) {                                 // 8 tokens x 16 e
    int tok = tid >> 4, e = tid & 15;
    int ww = tok >> 1, tt = tok & 1;
    float s = 0.f;
#pragma unroll
    for (int grp = 0; grp < 8; ++grp)
      s += glds[((ww * 8 + grp) * 2 + tt) * 16 + e];
    ws[(size_t)(t0 + tok) * NE + e] = s;           // contiguous 512B/block
  }
}

// Full logits in ws: top-2 (earliest-index tie-break = jax top_k), sigmoid,
// scatter into (E,N) scores; token_indices[e][t] = t (as float).
__global__ __launch_bounds__(256)
void router_finalize(const float* __restrict__ ws, float* __restrict__ out) {
  int t = blockIdx.x * 256 + threadIdx.x;
  const float4* row = (const float4*)(ws + (size_t)t * NE);
  float4 r0 = row[0], r1 = row[1], r2 = row[2], r3 = row[3];
  float l[NE] = {r0.x, r0.y, r0.z, r0.w, r1.x, r1.y, r1.z, r1.w,
                 r2.x, r2.y, r2.z, r2.w, r3.x, r3.y, r3.z, r3.w};
  int i1 = 0; float v1 = l[0];
#pragma unroll
  for (int e = 1; e < NE; ++e) { if (l[e] > v1) { v1 = l[e]; i1 = e; } }
  int i2 = -1; float v2 = -1e30f;
#pragma unroll
  for (int e = 0; e < NE; ++e) { if (e != i1 && l[e] > v2) { v2 = l[e]; i2 = e; } }
  float s1 = 1.f / (1.f + __expf(-v1));
  float s2 = 1.f / (1.f + __expf(-v2));
  float* scores = out;
  float* tix    = out + (size_t)NE * N_TOK;
  float tf = (float)t;
#pragma unroll
  for (int e = 0; e < NE; ++e) {                   // coalesced across lanes per e
    scores[(size_t)e * N_TOK + t] = (e == i1) ? s1 : ((e == i2) ? s2 : 0.f);
    tix[(size_t)e * N_TOK + t]    = tf;
  }
}

extern "C" void kernel_launch(void* const* d_in, const int* in_sizes, int n_in,
                              void* d_out, int out_size, void* d_ws, size_t ws_size,
                              hipStream_t stream) {
  const float* x    = (const float*)d_in[0];
  const float* gate = (const float*)d_in[1];
  float* out = (float*)d_out;
  float* ws  = (float*)d_ws;   // needs N_TOK*NE*4 = 512 KB (full logits)
  router_logits<<<dim3(N_TOK / TPB), dim3(256), 0, stream>>>(x, gate, ws);
  router_finalize<<<dim3(N_TOK / 256), dim3(256), 0, stream>>>(ws, out);
}